// Round 15
// baseline (132.110 us; speedup 1.0000x reference)
//
#include <hip/hip_runtime.h>

// Armor: strict IEEE semantics (validated R10-R14). Arithmetic contract frozen:
// mul+add einsum -> pairwise pool -> seq-k FMA DCT -> scale mul -> recip-mul -> rintf.
#pragma float_control(precise, on)

__device__ __forceinline__ float readlane_f(float v, int k) {
    return __uint_as_float((unsigned)__builtin_amdgcn_readlane((int)__float_as_uint(v), k));
}

extern "C" __global__ void __launch_bounds__(256, 4)
jpeg_compress(const float* __restrict__ image,
              const float* __restrict__ matrix,
              const float* __restrict__ shiftv,
              const float* __restrict__ y_table,
              const float* __restrict__ c_table,
              const float* __restrict__ dct_tensor,
              const float* __restrict__ dct_scale,
              const int*   __restrict__ factor,
              float* __restrict__ out)
{
    const int t    = threadIdx.x;
    const int lane = t & 63;
    const int wave = t >> 6;
    const int wg   = blockIdx.x;
    const int img  = wg >> 10;
    const int tile = wg & 1023;
    const int ty   = tile >> 5;
    const int tx   = tile & 31;

    __shared__ __align__(16) float ylds[16 * 64];   // 16 Y blocks, block-major
    __shared__ __align__(16) float clds[8 * 64];    // 4 Cb blocks then 4 Cr blocks

    const float m00 = matrix[0], m01 = matrix[1], m02 = matrix[2];
    const float m10 = matrix[3], m11 = matrix[4], m12 = matrix[5];
    const float m20 = matrix[6], m21 = matrix[7], m22 = matrix[8];
    const float s0 = shiftv[0], s1 = shiftv[1], s2 = shiftv[2];

    // ---- phase 1: load 32x32 RGB tile, YCbCr, pool chroma, stage to LDS ----
    const int row = t >> 3;            // 0..31
    const int c0  = (t & 7) << 2;      // 0..28 step 4
    const float* p = image + (size_t)img * 3145728u
                   + (size_t)(ty * 32 + row) * 1024 + (size_t)(tx * 32 + c0);
    float4 R4 = *(const float4*)p;
    float4 G4 = *(const float4*)(p + 1048576);
    float4 B4 = *(const float4*)(p + 2097152);

    float yv[4], cbv[4], crv[4];
    {
        #pragma clang fp contract(off)
        float Rr[4] = {R4.x, R4.y, R4.z, R4.w};
        float Gg[4] = {G4.x, G4.y, G4.z, G4.w};
        float Bb[4] = {B4.x, B4.y, B4.z, B4.w};
        #pragma unroll
        for (int j = 0; j < 4; ++j) {
            float R = Rr[j] * 255.0f, G = Gg[j] * 255.0f, B = Bb[j] * 255.0f;
            // VALIDATED: einsum = sequential c, mul then add (no fma), + shift separate
            yv[j]  = (((R * m00 + G * m10) + B * m20) + s0) - 128.0f;
            cbv[j] =  ((R * m01 + G * m11) + B * m21) + s1;
            crv[j] =  ((R * m02 + G * m12) + B * m22) + s2;
        }
    }

    {
        const int yblk = ((row >> 3) << 2) + (c0 >> 3);
        const int yk   = ((row & 7) << 3) + (c0 & 7);
        *(float4*)&ylds[yblk * 64 + yk] = make_float4(yv[0], yv[1], yv[2], yv[3]);
    }

    float bcb[4], bcr[4];
    #pragma unroll
    for (int j = 0; j < 4; ++j) {
        bcb[j] = __shfl_down(cbv[j], 8, 64);
        bcr[j] = __shfl_down(crv[j], 8, 64);
    }
    if ((row & 1) == 0) {
        #pragma clang fp contract(off)
        // VALIDATED: pairwise pool (x00+x01)+(x10+x11), exact /4, -128
        float p0cb = (((cbv[0] + cbv[1]) + (bcb[0] + bcb[1])) / 4.0f) - 128.0f;
        float p1cb = (((cbv[2] + cbv[3]) + (bcb[2] + bcb[3])) / 4.0f) - 128.0f;
        float p0cr = (((crv[0] + crv[1]) + (bcr[0] + bcr[1])) / 4.0f) - 128.0f;
        float p1cr = (((crv[2] + crv[3]) + (bcr[2] + bcr[3])) / 4.0f) - 128.0f;
        const int pr = row >> 1;           // 0..15
        const int pc = (t & 7) << 1;       // 0..14 step 2
        const int cblk = ((pr >> 3) << 1) + (pc >> 3);
        const int kk = ((pr & 7) << 3) + (pc & 7);
        clds[cblk * 64 + kk]           = p0cb;
        clds[cblk * 64 + kk + 1]       = p1cb;
        clds[(4 + cblk) * 64 + kk]     = p0cr;
        clds[(4 + cblk) * 64 + kk + 1] = p1cr;
    }
    __syncthreads();

    // ---- load DCT column AFTER phase 1 (minimal liveness) and PIN in VGPRs ----
    // VGPR 52 in R14 proved the compiler rematerialized these loads inside the
    // FMA chain (6x re-load per wave + vmcnt waits). The opaque asm def forbids
    // remat; __launch_bounds__(256,4) gives the 128-VGPR budget to hold them.
    float wcol[64];
    #pragma unroll
    for (int k = 0; k < 64; ++k) wcol[k] = dct_tensor[k * 64 + lane];
    #pragma unroll
    for (int k = 0; k < 64; ++k) asm volatile("" : "+v"(wcol[k]));

    const float scale_l = dct_scale[lane];
    const float fac = (float)factor[0];
    // VALIDATED: reciprocal-multiply quantize, f32
    const float rqy = 1.0f / (y_table[lane] * fac);
    const float rqc = 1.0f / (c_table[lane] * fac);

    // ---- phase 2: per-wave DCT + quantize of 6 blocks ----
    #pragma unroll
    for (int i = 0; i < 6; ++i) {
        const int blk = wave * 6 + i;      // 0..23
        const float* src;
        float rqt;
        size_t obase;
        if (blk < 16) {
            src = &ylds[blk * 64];
            rqt = rqy;
            const int gbr = ty * 4 + (blk >> 2);
            const int gbc = tx * 4 + (blk & 3);
            obase = ((size_t)img * 16384 + (size_t)(gbr * 128 + gbc)) * 64;
        } else {
            const int cb = blk - 16;       // 0..7: 0-3 Cb, 4-7 Cr
            src = &clds[cb * 64];
            rqt = rqc;
            const int cc = cb & 3;
            const int gbr = ty * 2 + (cc >> 1);
            const int gbc = tx * 2 + (cc & 1);
            obase = (size_t)16777216u + (size_t)(cb >> 2) * 4194304u
                  + ((size_t)img * 4096 + (size_t)(gbr * 64 + gbc)) * 64;
        }
        const float rb = src[lane];        // lane l holds b[l]; wave-uniform vector
        float acc = 0.0f;
        // VALIDATED: flat 64-term dot, k ascending, single accumulator, FMA
        #pragma unroll
        for (int k = 0; k < 64; ++k)
            acc = fmaf(readlane_f(rb, k), wcol[k], acc);
        const float d = scale_l * acc;     // f32
        {
            #pragma clang fp contract(off)
            out[obase + lane] = rintf(d * rqt);   // recip-mul + half-even round
        }
    }
}

extern "C" void kernel_launch(void* const* d_in, const int* in_sizes, int n_in,
                              void* d_out, int out_size, void* d_ws, size_t ws_size,
                              hipStream_t stream)
{
    const float* image   = (const float*)d_in[0];
    const float* matrix  = (const float*)d_in[1];
    const float* shiftv  = (const float*)d_in[2];
    const float* y_table = (const float*)d_in[3];
    const float* c_table = (const float*)d_in[4];
    const float* dct_t   = (const float*)d_in[5];
    const float* dct_s   = (const float*)d_in[6];
    const int*   factor  = (const int*)d_in[7];
    jpeg_compress<<<dim3(16384), dim3(256), 0, stream>>>(
        image, matrix, shiftv, y_table, c_table, dct_t, dct_s, factor,
        (float*)d_out);
}

// Round 16
// 128.190 us; speedup vs baseline: 1.0306x; 1.0306x over previous
//
#include <hip/hip_runtime.h>
#include <utility>

// Armor: strict IEEE semantics (validated R10-R14). Arithmetic contract frozen:
// mul+add einsum -> pairwise pool -> seq-k FMA DCT -> scale mul -> recip-mul -> rintf.
#pragma float_control(precise, on)

__device__ __forceinline__ float readlane_f(float v, int k) {
    return __uint_as_float((unsigned)__builtin_amdgcn_readlane((int)__float_as_uint(v), k));
}

// Guaranteed-unrolled 64-term chain with compile-time lane indices.
// Comma-fold preserves strict left-to-right (k-ascending) order -> frozen assoc.
template <int... Ks>
__device__ __forceinline__ float dct64_chain(float rb, const float* w,
                                             std::integer_sequence<int, Ks...>) {
    float acc = 0.0f;
    ((acc = fmaf(readlane_f(rb, Ks), w[Ks], acc)), ...);
    return acc;
}

template <int... Ks>
__device__ __forceinline__ void load_wcol(float* w, const float* __restrict__ g,
                                          int lane, std::integer_sequence<int, Ks...>) {
    ((w[Ks] = g[Ks * 64 + lane]), ...);
}

extern "C" __global__ void __launch_bounds__(256, 4)
jpeg_compress(const float* __restrict__ image,
              const float* __restrict__ matrix,
              const float* __restrict__ shiftv,
              const float* __restrict__ y_table,
              const float* __restrict__ c_table,
              const float* __restrict__ dct_tensor,
              const float* __restrict__ dct_scale,
              const int*   __restrict__ factor,
              float* __restrict__ out)
{
    const int t    = threadIdx.x;
    const int lane = t & 63;
    const int wave = t >> 6;
    const int wg   = blockIdx.x;
    const int img  = wg >> 10;
    const int tile = wg & 1023;
    const int ty   = tile >> 5;
    const int tx   = tile & 31;

    __shared__ __align__(16) float ylds[16 * 64];   // 16 Y blocks, block-major
    __shared__ __align__(16) float clds[8 * 64];    // 4 Cb blocks then 4 Cr blocks

    const float m00 = matrix[0], m01 = matrix[1], m02 = matrix[2];
    const float m10 = matrix[3], m11 = matrix[4], m12 = matrix[5];
    const float m20 = matrix[6], m21 = matrix[7], m22 = matrix[8];
    const float s0 = shiftv[0], s1 = shiftv[1], s2 = shiftv[2];

    // ---- phase 1: load 32x32 RGB tile, YCbCr, pool chroma, stage to LDS ----
    const int row = t >> 3;            // 0..31
    const int c0  = (t & 7) << 2;      // 0..28 step 4
    const float* p = image + (size_t)img * 3145728u
                   + (size_t)(ty * 32 + row) * 1024 + (size_t)(tx * 32 + c0);
    float4 R4 = *(const float4*)p;
    float4 G4 = *(const float4*)(p + 1048576);
    float4 B4 = *(const float4*)(p + 2097152);

    float yv[4], cbv[4], crv[4];
    {
        #pragma clang fp contract(off)
        float Rr[4] = {R4.x, R4.y, R4.z, R4.w};
        float Gg[4] = {G4.x, G4.y, G4.z, G4.w};
        float Bb[4] = {B4.x, B4.y, B4.z, B4.w};
        #pragma unroll
        for (int j = 0; j < 4; ++j) {
            float R = Rr[j] * 255.0f, G = Gg[j] * 255.0f, B = Bb[j] * 255.0f;
            // VALIDATED: einsum = sequential c, mul then add (no fma), + shift separate
            yv[j]  = (((R * m00 + G * m10) + B * m20) + s0) - 128.0f;
            cbv[j] =  ((R * m01 + G * m11) + B * m21) + s1;
            crv[j] =  ((R * m02 + G * m12) + B * m22) + s2;
        }
    }

    {
        const int yblk = ((row >> 3) << 2) + (c0 >> 3);
        const int yk   = ((row & 7) << 3) + (c0 & 7);
        *(float4*)&ylds[yblk * 64 + yk] = make_float4(yv[0], yv[1], yv[2], yv[3]);
    }

    float bcb[4], bcr[4];
    #pragma unroll
    for (int j = 0; j < 4; ++j) {
        bcb[j] = __shfl_down(cbv[j], 8, 64);
        bcr[j] = __shfl_down(crv[j], 8, 64);
    }
    if ((row & 1) == 0) {
        #pragma clang fp contract(off)
        // VALIDATED: pairwise pool (x00+x01)+(x10+x11), exact /4, -128
        float p0cb = (((cbv[0] + cbv[1]) + (bcb[0] + bcb[1])) / 4.0f) - 128.0f;
        float p1cb = (((cbv[2] + cbv[3]) + (bcb[2] + bcb[3])) / 4.0f) - 128.0f;
        float p0cr = (((crv[0] + crv[1]) + (bcr[0] + bcr[1])) / 4.0f) - 128.0f;
        float p1cr = (((crv[2] + crv[3]) + (bcr[2] + bcr[3])) / 4.0f) - 128.0f;
        const int pr = row >> 1;           // 0..15
        const int pc = (t & 7) << 1;       // 0..14 step 2
        const int cblk = ((pr >> 3) << 1) + (pc >> 3);
        const int kk = ((pr & 7) << 3) + (pc & 7);
        clds[cblk * 64 + kk]           = p0cb;
        clds[cblk * 64 + kk + 1]       = p1cb;
        clds[(4 + cblk) * 64 + kk]     = p0cr;
        clds[(4 + cblk) * 64 + kk + 1] = p1cr;
    }
    __syncthreads();

    // ---- DCT column loaded AFTER phase 1 with constant indices -> SROA -> VGPRs ----
    float wcol[64];
    load_wcol(wcol, dct_tensor, lane, std::make_integer_sequence<int, 64>{});

    const float scale_l = dct_scale[lane];
    const float fac = (float)factor[0];
    // VALIDATED: reciprocal-multiply quantize, f32
    const float rqy = 1.0f / (y_table[lane] * fac);
    const float rqc = 1.0f / (c_table[lane] * fac);

    // ---- phase 2: per-wave DCT + quantize of 6 blocks ----
    #pragma unroll
    for (int i = 0; i < 6; ++i) {
        const int blk = wave * 6 + i;      // 0..23
        const float* src;
        float rqt;
        size_t obase;
        if (blk < 16) {
            src = &ylds[blk * 64];
            rqt = rqy;
            const int gbr = ty * 4 + (blk >> 2);
            const int gbc = tx * 4 + (blk & 3);
            obase = ((size_t)img * 16384 + (size_t)(gbr * 128 + gbc)) * 64;
        } else {
            const int cb = blk - 16;       // 0..7: 0-3 Cb, 4-7 Cr
            src = &clds[cb * 64];
            rqt = rqc;
            const int cc = cb & 3;
            const int gbr = ty * 2 + (cc >> 1);
            const int gbc = tx * 2 + (cc & 1);
            obase = (size_t)16777216u + (size_t)(cb >> 2) * 4194304u
                  + ((size_t)img * 4096 + (size_t)(gbr * 64 + gbc)) * 64;
        }
        const float rb = src[lane];        // lane l holds b[l]; wave-uniform vector
        // VALIDATED: flat 64-term dot, k ascending, single accumulator, FMA
        const float acc = dct64_chain(rb, wcol, std::make_integer_sequence<int, 64>{});
        const float d = scale_l * acc;     // f32
        {
            #pragma clang fp contract(off)
            out[obase + lane] = rintf(d * rqt);   // recip-mul + half-even round
        }
    }
}

extern "C" void kernel_launch(void* const* d_in, const int* in_sizes, int n_in,
                              void* d_out, int out_size, void* d_ws, size_t ws_size,
                              hipStream_t stream)
{
    const float* image   = (const float*)d_in[0];
    const float* matrix  = (const float*)d_in[1];
    const float* shiftv  = (const float*)d_in[2];
    const float* y_table = (const float*)d_in[3];
    const float* c_table = (const float*)d_in[4];
    const float* dct_t   = (const float*)d_in[5];
    const float* dct_s   = (const float*)d_in[6];
    const int*   factor  = (const int*)d_in[7];
    jpeg_compress<<<dim3(16384), dim3(256), 0, stream>>>(
        image, matrix, shiftv, y_table, c_table, dct_t, dct_s, factor,
        (float*)d_out);
}

// Round 18
// 100.482 us; speedup vs baseline: 1.3148x; 1.2757x over previous
//
#include <hip/hip_runtime.h>

// Armor: strict IEEE semantics (validated R10-R14). Arithmetic contract frozen:
// mul+add einsum -> pairwise pool -> seq-k FMA DCT -> scale mul -> recip-mul -> rintf.
#pragma float_control(precise, on)

// ---- 64 NAMED weight registers: no array, no SROA, no remat (asm def) ----
#define LW(k) float w##k = dct_tensor[(k) * 64 + lane]; asm("" : "+v"(w##k));

// One block's 4-term sub-chain for k-group k4 (k ascending, single acc, fmaf).
// b fetched as a lane-uniform float4 from LDS (native same-address broadcast);
// values are bit-identical to the former readlane scheme.
#define STEP4(i, k4, W0, W1, W2, W3) {                                  \
    const float4 bq = *(const float4*)(bp##i + (k4) * 4);               \
    ac##i = fmaf(bq.x, W0, ac##i); ac##i = fmaf(bq.y, W1, ac##i);       \
    ac##i = fmaf(bq.z, W2, ac##i); ac##i = fmaf(bq.w, W3, ac##i); }

#define GROUP(k4, W0, W1, W2, W3)                                       \
    STEP4(0, k4, W0, W1, W2, W3) STEP4(1, k4, W0, W1, W2, W3)           \
    STEP4(2, k4, W0, W1, W2, W3) STEP4(3, k4, W0, W1, W2, W3)           \
    STEP4(4, k4, W0, W1, W2, W3) STEP4(5, k4, W0, W1, W2, W3)

#define SETUP(i) \
    const float* bp##i; float qr##i; size_t ob##i; float ac##i = 0.0f;   \
    { const int blk = wave * 6 + i;                                      \
      if (blk < 16) {                                                    \
          bp##i = &ylds[blk * 64]; qr##i = rqy;                          \
          const int gbr = ty * 4 + (blk >> 2);                           \
          const int gbc = tx * 4 + (blk & 3);                            \
          ob##i = ((size_t)img * 16384 + (size_t)(gbr * 128 + gbc)) * 64;\
      } else {                                                           \
          const int cb = blk - 16;                                       \
          bp##i = &clds[cb * 64]; qr##i = rqc;                           \
          const int cc = cb & 3;                                         \
          const int gbr = ty * 2 + (cc >> 1);                            \
          const int gbc = tx * 2 + (cc & 1);                             \
          ob##i = (size_t)16777216u + (size_t)(cb >> 2) * 4194304u       \
                + ((size_t)img * 4096 + (size_t)(gbr * 64 + gbc)) * 64;  \
      } }

#define FIN(i) { const float dd = scale_l * ac##i;                       \
                 out[ob##i + lane] = rintf(dd * qr##i); }

extern "C" __global__ void __launch_bounds__(256, 4)
jpeg_compress(const float* __restrict__ image,
              const float* __restrict__ matrix,
              const float* __restrict__ shiftv,
              const float* __restrict__ y_table,
              const float* __restrict__ c_table,
              const float* __restrict__ dct_tensor,
              const float* __restrict__ dct_scale,
              const int*   __restrict__ factor,
              float* __restrict__ out)
{
    const int t    = threadIdx.x;
    const int lane = t & 63;
    const int wave = t >> 6;
    const int wg   = blockIdx.x;
    const int img  = wg >> 10;
    const int tile = wg & 1023;
    const int ty   = tile >> 5;
    const int tx   = tile & 31;

    __shared__ __align__(16) float ylds[16 * 64];   // 16 Y blocks, block-major
    __shared__ __align__(16) float clds[8 * 64];    // 4 Cb blocks then 4 Cr blocks

    const float m00 = matrix[0], m01 = matrix[1], m02 = matrix[2];
    const float m10 = matrix[3], m11 = matrix[4], m12 = matrix[5];
    const float m20 = matrix[6], m21 = matrix[7], m22 = matrix[8];
    const float sh0 = shiftv[0], sh1 = shiftv[1], sh2 = shiftv[2];

    // ---- phase 1: load 32x32 RGB tile, YCbCr, pool chroma, stage to LDS ----
    const int row = t >> 3;            // 0..31
    const int c0  = (t & 7) << 2;      // 0..28 step 4
    const float* p = image + (size_t)img * 3145728u
                   + (size_t)(ty * 32 + row) * 1024 + (size_t)(tx * 32 + c0);
    float4 R4 = *(const float4*)p;
    float4 G4 = *(const float4*)(p + 1048576);
    float4 B4 = *(const float4*)(p + 2097152);

    float yv[4], cbv[4], crv[4];
    {
        #pragma clang fp contract(off)
        float Rr[4] = {R4.x, R4.y, R4.z, R4.w};
        float Gg[4] = {G4.x, G4.y, G4.z, G4.w};
        float Bb[4] = {B4.x, B4.y, B4.z, B4.w};
        #pragma unroll
        for (int j = 0; j < 4; ++j) {
            float R = Rr[j] * 255.0f, G = Gg[j] * 255.0f, B = Bb[j] * 255.0f;
            // VALIDATED: einsum = sequential c, mul then add (no fma), + shift separate
            yv[j]  = (((R * m00 + G * m10) + B * m20) + sh0) - 128.0f;
            cbv[j] =  ((R * m01 + G * m11) + B * m21) + sh1;
            crv[j] =  ((R * m02 + G * m12) + B * m22) + sh2;
        }
    }

    {
        const int yblk = ((row >> 3) << 2) + (c0 >> 3);
        const int yk   = ((row & 7) << 3) + (c0 & 7);
        *(float4*)&ylds[yblk * 64 + yk] = make_float4(yv[0], yv[1], yv[2], yv[3]);
    }

    float bcb[4], bcr[4];
    #pragma unroll
    for (int j = 0; j < 4; ++j) {
        bcb[j] = __shfl_down(cbv[j], 8, 64);
        bcr[j] = __shfl_down(crv[j], 8, 64);
    }
    if ((row & 1) == 0) {
        #pragma clang fp contract(off)
        // VALIDATED: pairwise pool (x00+x01)+(x10+x11), exact /4, -128
        float p0cb = (((cbv[0] + cbv[1]) + (bcb[0] + bcb[1])) / 4.0f) - 128.0f;
        float p1cb = (((cbv[2] + cbv[3]) + (bcb[2] + bcb[3])) / 4.0f) - 128.0f;
        float p0cr = (((crv[0] + crv[1]) + (bcr[0] + bcr[1])) / 4.0f) - 128.0f;
        float p1cr = (((crv[2] + crv[3]) + (bcr[2] + bcr[3])) / 4.0f) - 128.0f;
        const int pr = row >> 1;           // 0..15
        const int pc = (t & 7) << 1;       // 0..14 step 2
        const int cblk = ((pr >> 3) << 1) + (pc >> 3);
        const int kk = ((pr & 7) << 3) + (pc & 7);
        clds[cblk * 64 + kk]           = p0cb;
        clds[cblk * 64 + kk + 1]       = p1cb;
        clds[(4 + cblk) * 64 + kk]     = p0cr;
        clds[(4 + cblk) * 64 + kk + 1] = p1cr;
    }
    __syncthreads();

    // ---- DCT weights: 64 NAMED scalar registers, loaded after phase 1 ----
    LW(0)  LW(1)  LW(2)  LW(3)  LW(4)  LW(5)  LW(6)  LW(7)
    LW(8)  LW(9)  LW(10) LW(11) LW(12) LW(13) LW(14) LW(15)
    LW(16) LW(17) LW(18) LW(19) LW(20) LW(21) LW(22) LW(23)
    LW(24) LW(25) LW(26) LW(27) LW(28) LW(29) LW(30) LW(31)
    LW(32) LW(33) LW(34) LW(35) LW(36) LW(37) LW(38) LW(39)
    LW(40) LW(41) LW(42) LW(43) LW(44) LW(45) LW(46) LW(47)
    LW(48) LW(49) LW(50) LW(51) LW(52) LW(53) LW(54) LW(55)
    LW(56) LW(57) LW(58) LW(59) LW(60) LW(61) LW(62) LW(63)

    const float scale_l = dct_scale[lane];
    const float fac = (float)factor[0];
    // VALIDATED: reciprocal-multiply quantize, f32
    const float rqy = 1.0f / (y_table[lane] * fac);
    const float rqc = 1.0f / (c_table[lane] * fac);

    // ---- phase 2: 6 blocks, explicit ILP-6, frozen k-ascending FMA chains ----
    SETUP(0) SETUP(1) SETUP(2) SETUP(3) SETUP(4) SETUP(5)

    GROUP(0,  w0,  w1,  w2,  w3)   GROUP(1,  w4,  w5,  w6,  w7)
    GROUP(2,  w8,  w9,  w10, w11)  GROUP(3,  w12, w13, w14, w15)
    GROUP(4,  w16, w17, w18, w19)  GROUP(5,  w20, w21, w22, w23)
    GROUP(6,  w24, w25, w26, w27)  GROUP(7,  w28, w29, w30, w31)
    GROUP(8,  w32, w33, w34, w35)  GROUP(9,  w36, w37, w38, w39)
    GROUP(10, w40, w41, w42, w43)  GROUP(11, w44, w45, w46, w47)
    GROUP(12, w48, w49, w50, w51)  GROUP(13, w52, w53, w54, w55)
    GROUP(14, w56, w57, w58, w59)  GROUP(15, w60, w61, w62, w63)

    FIN(0) FIN(1) FIN(2) FIN(3) FIN(4) FIN(5)
}

extern "C" void kernel_launch(void* const* d_in, const int* in_sizes, int n_in,
                              void* d_out, int out_size, void* d_ws, size_t ws_size,
                              hipStream_t stream)
{
    const float* image   = (const float*)d_in[0];
    const float* matrix  = (const float*)d_in[1];
    const float* shiftv  = (const float*)d_in[2];
    const float* y_table = (const float*)d_in[3];
    const float* c_table = (const float*)d_in[4];
    const float* dct_t   = (const float*)d_in[5];
    const float* dct_s   = (const float*)d_in[6];
    const int*   factor  = (const int*)d_in[7];
    jpeg_compress<<<dim3(16384), dim3(256), 0, stream>>>(
        image, matrix, shiftv, y_table, c_table, dct_t, dct_s, factor,
        (float*)d_out);
}

// Round 19
// 94.969 us; speedup vs baseline: 1.3911x; 1.0581x over previous
//
#include <hip/hip_runtime.h>

// Armor: strict IEEE semantics (validated R10-R14). Arithmetic contract frozen:
// mul+add einsum -> pairwise pool -> seq-k FMA DCT -> scale mul -> recip-mul -> rintf.
#pragma float_control(precise, on)

// One block's 4-term sub-chain for k-group g (k ascending, single acc, fmaf).
// b fetched as a lane-uniform float4 from LDS (native same-address broadcast).
#define STEP4(i, g, W0, W1, W2, W3) {                                   \
    const float4 bq = *(const float4*)(bp##i + (g) * 4);                \
    ac##i = fmaf(bq.x, W0, ac##i); ac##i = fmaf(bq.y, W1, ac##i);       \
    ac##i = fmaf(bq.z, W2, ac##i); ac##i = fmaf(bq.w, W3, ac##i); }

// Weights loaded AT USE from the L1-resident 16KB table (R18 codegen showed the
// allocator prefers refetch over residency; expressing it directly frees VGPRs
// for 8-waves/SIMD occupancy).
#define GROUP(g) {                                                      \
    const float W0 = dct_tensor[((g) * 4 + 0) * 64 + lane];             \
    const float W1 = dct_tensor[((g) * 4 + 1) * 64 + lane];             \
    const float W2 = dct_tensor[((g) * 4 + 2) * 64 + lane];             \
    const float W3 = dct_tensor[((g) * 4 + 3) * 64 + lane];             \
    STEP4(0, g, W0, W1, W2, W3) STEP4(1, g, W0, W1, W2, W3)             \
    STEP4(2, g, W0, W1, W2, W3) STEP4(3, g, W0, W1, W2, W3)             \
    STEP4(4, g, W0, W1, W2, W3) STEP4(5, g, W0, W1, W2, W3) }

#define SETUP(i) \
    const float* bp##i; float qr##i; size_t ob##i; float ac##i = 0.0f;   \
    { const int blk = wave * 6 + i;                                      \
      if (blk < 16) {                                                    \
          bp##i = &ylds[blk * 64]; qr##i = rqy;                          \
          const int gbr = ty * 4 + (blk >> 2);                           \
          const int gbc = tx * 4 + (blk & 3);                            \
          ob##i = ((size_t)img * 16384 + (size_t)(gbr * 128 + gbc)) * 64;\
      } else {                                                           \
          const int cb = blk - 16;                                       \
          bp##i = &clds[cb * 64]; qr##i = rqc;                           \
          const int cc = cb & 3;                                         \
          const int gbr = ty * 2 + (cc >> 1);                            \
          const int gbc = tx * 2 + (cc & 1);                             \
          ob##i = (size_t)16777216u + (size_t)(cb >> 2) * 4194304u       \
                + ((size_t)img * 4096 + (size_t)(gbr * 64 + gbc)) * 64;  \
      } }

#define FIN(i) { const float dd = scale_l * ac##i;                       \
                 out[ob##i + lane] = rintf(dd * qr##i); }

extern "C" __global__ void __launch_bounds__(256, 8)
jpeg_compress(const float* __restrict__ image,
              const float* __restrict__ matrix,
              const float* __restrict__ shiftv,
              const float* __restrict__ y_table,
              const float* __restrict__ c_table,
              const float* __restrict__ dct_tensor,
              const float* __restrict__ dct_scale,
              const int*   __restrict__ factor,
              float* __restrict__ out)
{
    const int t    = threadIdx.x;
    const int lane = t & 63;
    const int wave = t >> 6;
    const int wg   = blockIdx.x;
    const int img  = wg >> 10;
    const int tile = wg & 1023;
    const int ty   = tile >> 5;
    const int tx   = tile & 31;

    __shared__ __align__(16) float ylds[16 * 64];   // 16 Y blocks, block-major
    __shared__ __align__(16) float clds[8 * 64];    // 4 Cb blocks then 4 Cr blocks

    const float m00 = matrix[0], m01 = matrix[1], m02 = matrix[2];
    const float m10 = matrix[3], m11 = matrix[4], m12 = matrix[5];
    const float m20 = matrix[6], m21 = matrix[7], m22 = matrix[8];
    const float sh0 = shiftv[0], sh1 = shiftv[1], sh2 = shiftv[2];

    // ---- phase 1: load 32x32 RGB tile, YCbCr, pool chroma, stage to LDS ----
    const int row = t >> 3;            // 0..31
    const int c0  = (t & 7) << 2;      // 0..28 step 4
    const float* p = image + (size_t)img * 3145728u
                   + (size_t)(ty * 32 + row) * 1024 + (size_t)(tx * 32 + c0);
    float4 R4 = *(const float4*)p;
    float4 G4 = *(const float4*)(p + 1048576);
    float4 B4 = *(const float4*)(p + 2097152);

    float yv[4], cbv[4], crv[4];
    {
        #pragma clang fp contract(off)
        float Rr[4] = {R4.x, R4.y, R4.z, R4.w};
        float Gg[4] = {G4.x, G4.y, G4.z, G4.w};
        float Bb[4] = {B4.x, B4.y, B4.z, B4.w};
        #pragma unroll
        for (int j = 0; j < 4; ++j) {
            float R = Rr[j] * 255.0f, G = Gg[j] * 255.0f, B = Bb[j] * 255.0f;
            // VALIDATED: einsum = sequential c, mul then add (no fma), + shift separate
            yv[j]  = (((R * m00 + G * m10) + B * m20) + sh0) - 128.0f;
            cbv[j] =  ((R * m01 + G * m11) + B * m21) + sh1;
            crv[j] =  ((R * m02 + G * m12) + B * m22) + sh2;
        }
    }

    {
        const int yblk = ((row >> 3) << 2) + (c0 >> 3);
        const int yk   = ((row & 7) << 3) + (c0 & 7);
        *(float4*)&ylds[yblk * 64 + yk] = make_float4(yv[0], yv[1], yv[2], yv[3]);
    }

    float bcb[4], bcr[4];
    #pragma unroll
    for (int j = 0; j < 4; ++j) {
        bcb[j] = __shfl_down(cbv[j], 8, 64);
        bcr[j] = __shfl_down(crv[j], 8, 64);
    }
    if ((row & 1) == 0) {
        #pragma clang fp contract(off)
        // VALIDATED: pairwise pool (x00+x01)+(x10+x11), exact /4, -128
        float p0cb = (((cbv[0] + cbv[1]) + (bcb[0] + bcb[1])) / 4.0f) - 128.0f;
        float p1cb = (((cbv[2] + cbv[3]) + (bcb[2] + bcb[3])) / 4.0f) - 128.0f;
        float p0cr = (((crv[0] + crv[1]) + (bcr[0] + bcr[1])) / 4.0f) - 128.0f;
        float p1cr = (((crv[2] + crv[3]) + (bcr[2] + bcr[3])) / 4.0f) - 128.0f;
        const int pr = row >> 1;           // 0..15
        const int pc = (t & 7) << 1;       // 0..14 step 2
        const int cblk = ((pr >> 3) << 1) + (pc >> 3);
        const int kk = ((pr & 7) << 3) + (pc & 7);
        clds[cblk * 64 + kk]           = p0cb;
        clds[cblk * 64 + kk + 1]       = p1cb;
        clds[(4 + cblk) * 64 + kk]     = p0cr;
        clds[(4 + cblk) * 64 + kk + 1] = p1cr;
    }
    __syncthreads();

    const float scale_l = dct_scale[lane];
    const float fac = (float)factor[0];
    // VALIDATED: reciprocal-multiply quantize, f32
    const float rqy = 1.0f / (y_table[lane] * fac);
    const float rqc = 1.0f / (c_table[lane] * fac);

    // ---- phase 2: 6 blocks, explicit ILP-6, frozen k-ascending FMA chains ----
    SETUP(0) SETUP(1) SETUP(2) SETUP(3) SETUP(4) SETUP(5)

    GROUP(0)  GROUP(1)  GROUP(2)  GROUP(3)
    GROUP(4)  GROUP(5)  GROUP(6)  GROUP(7)
    GROUP(8)  GROUP(9)  GROUP(10) GROUP(11)
    GROUP(12) GROUP(13) GROUP(14) GROUP(15)

    FIN(0) FIN(1) FIN(2) FIN(3) FIN(4) FIN(5)
}

extern "C" void kernel_launch(void* const* d_in, const int* in_sizes, int n_in,
                              void* d_out, int out_size, void* d_ws, size_t ws_size,
                              hipStream_t stream)
{
    const float* image   = (const float*)d_in[0];
    const float* matrix  = (const float*)d_in[1];
    const float* shiftv  = (const float*)d_in[2];
    const float* y_table = (const float*)d_in[3];
    const float* c_table = (const float*)d_in[4];
    const float* dct_t   = (const float*)d_in[5];
    const float* dct_s   = (const float*)d_in[6];
    const int*   factor  = (const int*)d_in[7];
    jpeg_compress<<<dim3(16384), dim3(256), 0, stream>>>(
        image, matrix, shiftv, y_table, c_table, dct_t, dct_s, factor,
        (float*)d_out);
}